// Round 6
// baseline (810.499 us; speedup 1.0000x reference)
//
#include <hip/hip_runtime.h>

#define NTRAIN 1024
#define NY 2
#define DDIM 128
#define NB 256
#define NITER 16
#define TT 1026          // NTRAIN + NY
#define TP 1088          // orig-index padding (for p/bl/xsq arrays)
#define CP 640           // class panel size (10*64); holds up to 639 train + 1 default
#define TPP (2*CP)       // 1280 permuted slots
#define SCALE_C 0.25f
#define GAMMA_C 0.05f
#define TAU_C 256.0f     // 2*D

typedef __attribute__((ext_vector_type(8))) __bf16 bf16x8;
typedef __attribute__((ext_vector_type(4))) float f32x4;

union FR { ushort4 u[2]; bf16x8 v; };

__device__ __forceinline__ float sigm(float x) {
    return 1.0f / (1.0f + __expf(-x));
}
__device__ __forceinline__ ushort bf2u(__bf16 b) {
    union { __bf16 b; ushort u; } x; x.b = b; return x.u;
}
__device__ __forceinline__ float u2f(ushort u) {
    union { __bf16 b; ushort u; } x; x.u = u; return (float)x.b;
}

// ---------------- prep: p, base_logit, xsq (orig index space) ----------------
__global__ void k_prep(const float* __restrict__ Xtr, const float* __restrict__ Xdef,
                       const float* __restrict__ worder, const float* __restrict__ wbase,
                       float* __restrict__ p, float* __restrict__ bl,
                       float* __restrict__ xsq) {
    int t = blockIdx.x;        // 0..TP-1
    int tx = threadIdx.x;      // 128 threads
    __shared__ float sp[128], sb[128], ss[128];
    float po = 0.f, bo = 0.f, sq = 0.f;
    if (t < TT) {
        const float* row = (t < NTRAIN) ? (Xtr + (size_t)t * DDIM)
                                        : (Xdef + (size_t)(t - NTRAIN) * DDIM);
        float x = row[tx];
        po = x * worder[tx];
        bo = x * wbase[tx];
        sq = x * x;
    }
    sp[tx] = po; sb[tx] = bo; ss[tx] = sq;
    __syncthreads();
    for (int off = 64; off > 0; off >>= 1) {
        if (tx < off) { sp[tx] += sp[tx+off]; sb[tx] += sb[tx+off]; ss[tx] += ss[tx+off]; }
        __syncthreads();
    }
    if (tx == 0) { p[t] = sp[0]; bl[t] = sb[0]; xsq[t] = ss[0]; }
}

// ---------------- label-sort permutation: map[slot] -> orig index (-1 = pad) ----------------
__global__ void k_perm(const int* __restrict__ ytr, const float* __restrict__ p,
                       int* __restrict__ map, float* __restrict__ pp) {
    __shared__ int ly[NTRAIN];
    int tid = threadIdx.x;                 // 1024 threads
    ly[tid] = ytr[tid];
    for (int a = tid; a < TPP; a += 1024) map[a] = -1;
    __syncthreads();
    int c = ly[tid];
    int rank = 0;
    for (int j = 0; j < NTRAIN; j++) {     // uniform loop, LDS broadcast
        int v = ly[j];
        if (j < tid && v == c) rank++;
    }
    if (rank < CP - 1) map[c * CP + rank] = tid;
    if (tid < NY) map[tid * CP + CP - 1] = NTRAIN + tid;
    __syncthreads();
    for (int a = tid; a < TPP; a += 1024) {
        int m = map[a];
        pp[a] = (m >= 0) ? p[m] : 0.f;
    }
}

// ---------------- Es'[a,b] = sigma(0.25(p_a-p_b))^2 in permuted space ----------------
__global__ void k_es2(const int* __restrict__ map, const float* __restrict__ pp,
                      float* __restrict__ Es) {
    int b = blockIdx.x * 256 + threadIdx.x;   // col slot
    int a = blockIdx.y;                       // row slot
    float v = 0.f;
    int mi = map[a], mj = map[b];
    if (mi >= 0 && mi < NTRAIN && mj >= 0) {
        float e = sigm(SCALE_C * (pp[a] - pp[b]));
        v = e * e;
    }
    Es[(size_t)a * TPP + b] = v;
}

// ---------------- partial blocked product, cross-panel only (unchanged r5) ----------------
#define KC 16
__global__ __launch_bounds__(256) void k_pblk2(const float* __restrict__ Es,
                                               float* __restrict__ P, int kspan) {
    __shared__ float Wt[KC][64 + 4];
    __shared__ float Et[KC][64 + 4];
    int c  = blockIdx.z & 1;
    int kz = blockIdx.z >> 1;
    int i0 = c * CP + blockIdx.y * 64;
    int j0 = (1 - c) * CP + blockIdx.x * 64;
    int ks = c * CP + kz * kspan, ke = ks + kspan;
    int tid = threadIdx.x;
    int tx = tid & 15, ty = tid >> 4;
    float prod[4][4];
    #pragma unroll
    for (int a = 0; a < 4; a++)
        #pragma unroll
        for (int b = 0; b < 4; b++) prod[a][b] = 1.f;

    for (int k0 = ks; k0 < ke; k0 += KC) {
        __syncthreads();
        #pragma unroll
        for (int e = tid; e < KC * 64; e += 256) {
            int kk = e & 15, ii = e >> 4;
            int gi = i0 + ii, gk = k0 + kk;
            float w = Es[(size_t)gi * TPP + gk];
            if (gi == gk) w = 0.f;
            Wt[kk][ii] = w;
        }
        #pragma unroll
        for (int e = tid; e < KC * 64; e += 256) {
            int jj = e & 63, kk = e >> 6;
            Et[kk][jj] = Es[(size_t)(k0 + kk) * TPP + j0 + jj];
        }
        __syncthreads();
        #pragma unroll
        for (int kk = 0; kk < KC; kk++) {
            float4 wv = *(const float4*)&Wt[kk][ty * 4];
            float4 ev = *(const float4*)&Et[kk][tx * 4];
            float w[4] = {wv.x, wv.y, wv.z, wv.w};
            float e[4] = {ev.x, ev.y, ev.z, ev.w};
            #pragma unroll
            for (int a = 0; a < 4; a++)
                #pragma unroll
                for (int b = 0; b < 4; b++)
                    prod[a][b] *= fmaf(-w[a], e[b], 1.f);
        }
    }
    float* Pz = P + (size_t)blockIdx.z * CP * CP;
    int jjl = blockIdx.x * 64 + tx * 4;
    #pragma unroll
    for (int a = 0; a < 4; a++) {
        int iil = blockIdx.y * 64 + ty * 4 + a;
        *(float4*)&Pz[(size_t)iil * CP + jjl] =
            make_float4(prod[a][0], prod[a][1], prod[a][2], prod[a][3]);
    }
}

// ---------------- combine partials + assemble A' (cross blocks only) ----------------
__global__ void k_afin2(const float* __restrict__ P, int psplit,
                        const int* __restrict__ map, const float* __restrict__ pp,
                        const float* __restrict__ Es, float* __restrict__ A) {
    size_t e = (size_t)blockIdx.x * 256 + threadIdx.x;
    int c = (int)(e / ((size_t)CP * CP));
    int rem = (int)(e % ((size_t)CP * CP));
    int iil = rem / CP, jjl = rem % CP;
    int a = c * CP + iil, b = (1 - c) * CP + jjl;
    float prod = P[(size_t)c * CP * CP + rem];
    for (int kz = 1; kz < psplit; kz++)
        prod *= P[(size_t)(kz * 2 + c) * CP * CP + rem];
    float v = 0.f;
    int mi = map[a], mj = map[b];
    if (mi >= 0 && mj >= 0) {
        float es = Es[(size_t)a * TPP + b];
        float x = SCALE_C * (pp[a] - pp[b]);
        float E = sigm(x);
        float sym = (mi < NTRAIN) ? E * (1.f - E) : 0.f;
        v = -(es * prod + sym);
    }
    A[(size_t)a * TPP + b] = v;
}

// ---------------- AT split: ATh/ATl[n][klocal] (bf16 hi/lo of A[k][n], opposite panel) ----------------
__global__ __launch_bounds__(256) void k_absplit(const float* __restrict__ A,
                                                 ushort* __restrict__ ATH,
                                                 ushort* __restrict__ ATL) {
    __shared__ float t[64][65];
    int n0 = blockIdx.y * 64;
    int d = (n0 >= CP) ? 1 : 0;
    int kg0 = (1 - d) * CP + blockIdx.x * 64;   // global k (opposite panel)
    int kl0 = blockIdx.x * 64;                  // local k in AT row
    int tid = threadIdx.x;
    for (int e = tid; e < 64 * 64; e += 256) {
        int r = e >> 6, c = e & 63;             // c fast -> coalesced A read
        t[r][c] = A[(size_t)(kg0 + r) * TPP + n0 + c];
    }
    __syncthreads();
    for (int e = tid; e < 64 * 64; e += 256) {
        int kk = e & 63, nn = e >> 6;           // kk fast -> coalesced writes
        float x = t[kk][nn];
        __bf16 h = (__bf16)x;
        size_t o = (size_t)(n0 + nn) * CP + kl0 + kk;
        ATH[o] = bf2u(h);
        ATL[o] = bf2u((__bf16)(x - (float)h));
    }
}

// ---------------- CT (f32) + S0 hi/lo bf16, permuted, row-major [NB][TPP] ----------------
__global__ void k_cq2(const float* __restrict__ Xtr, const float* __restrict__ Xdef,
                      const float* __restrict__ Xq, const float* __restrict__ bl,
                      const int* __restrict__ map,
                      float* __restrict__ CT, ushort* __restrict__ SH,
                      ushort* __restrict__ SL) {
    int bq = blockIdx.y;
    int t = blockIdx.x * 256 + threadIdx.x;
    int mi = map[t];
    float cv = 0.f, sv = 0.f;
    if (mi >= 0) {
        const float4* q4 = (const float4*)(Xq + (size_t)bq * DDIM);
        const float* row = (mi < NTRAIN) ? (Xtr + (size_t)mi * DDIM)
                                         : (Xdef + (size_t)(mi - NTRAIN) * DDIM);
        const float4* x4 = (const float4*)row;
        float dot = 0.f, qs = 0.f, xs = 0.f;
        #pragma unroll
        for (int d = 0; d < DDIM / 4; d++) {
            float4 q = q4[d], x = x4[d];
            dot = fmaf(q.x, x.x, fmaf(q.y, x.y, fmaf(q.z, x.z, fmaf(q.w, x.w, dot))));
            qs  = fmaf(q.x, q.x, fmaf(q.y, q.y, fmaf(q.z, q.z, fmaf(q.w, q.w, qs))));
            xs  = fmaf(x.x, x.x, fmaf(x.y, x.y, fmaf(x.z, x.z, fmaf(x.w, x.w, xs))));
        }
        float sq = qs + xs - 2.f * dot;
        float r = sigm(GAMMA_C * (sq - TAU_C));
        cv = bl[mi] - r;
        sv = sigm(bl[mi]);
    }
    size_t o = (size_t)bq * TPP + t;
    CT[o] = cv;
    __bf16 h = (__bf16)sv;
    SH[o] = bf2u(h);
    SL[o] = bf2u((__bf16)(sv - (float)h));
}

// ---------------- MFMA A/B fragment-layout probe (exact-integer self-check) ----------------
__device__ __forceinline__ float Aval(int m, int k) { return (float)((3*m + 7*k) % 13 - 6); }
__device__ __forceinline__ float Bval(int k, int n) { return (float)((5*k + 11*n) % 9 - 4); }

__global__ void k_probe(int* __restrict__ flag) {
    int lane = threadIdx.x;        // 1 wave
    int lg = lane >> 4, li = lane & 15;
    // hypothesis H0 (two-half): k = 4*lg + j (j<4), 16 + 4*lg + (j-4)
    FR fa, fb;
    #pragma unroll
    for (int j = 0; j < 8; j++) {
        int k = (j < 4) ? (4*lg + j) : (16 + 4*lg + (j - 4));
        fa.v[j] = (__bf16)Aval(li, k);
        fb.v[j] = (__bf16)Bval(k, li);
    }
    f32x4 acc = {0.f, 0.f, 0.f, 0.f};
    acc = __builtin_amdgcn_mfma_f32_16x16x32_bf16(fa.v, fb.v, acc, 0, 0, 0);
    int ok = 1;
    #pragma unroll
    for (int r = 0; r < 4; r++) {
        int row = 4*lg + r, col = li;
        float ref = 0.f;
        for (int k = 0; k < 32; k++) ref += Aval(row, k) * Bval(k, col);
        if (acc[r] != ref) ok = 0;
    }
    int allok = __all(ok);
    if (lane == 0) *flag = allok ? 0 : 1;   // 0 -> H0, 1 -> H1 (k = 8*lg + j)
}

// ---------------- one iteration, MFMA: Snew = sigma(CT + S@A'), fused ----------------
// grid (TPP/16, NB/64), 256 thr = 4 waves; wave -> 16x16 tile, K=640 (opposite panel).
__global__ __launch_bounds__(256) void k_imfma(const ushort* __restrict__ SH,
                                               const ushort* __restrict__ SL,
                                               const ushort* __restrict__ ATH,
                                               const ushort* __restrict__ ATL,
                                               const float* __restrict__ CT,
                                               const int* __restrict__ map,
                                               const int* __restrict__ flag,
                                               ushort* __restrict__ NH,
                                               ushort* __restrict__ NL) {
    int tid = threadIdx.x;
    int wv = tid >> 6, lane = tid & 63;
    int lg = lane >> 4, li = lane & 15;
    int m0 = blockIdx.y * 64 + wv * 16;
    int n0 = blockIdx.x * 16;
    int col = n0 + li;
    int hyp = *flag;
    int o0 = hyp ? (8*lg)     : (4*lg);
    int o1 = hyp ? (8*lg + 4) : (16 + 4*lg);
    int kb = (n0 >= CP) ? 0 : CP;              // k over OPPOSITE panel (global slots)
    const ushort* sh = SH + (size_t)(m0 + li) * TPP + kb;
    const ushort* sl = SL + (size_t)(m0 + li) * TPP + kb;
    const ushort* ah = ATH + (size_t)col * CP;
    const ushort* al = ATL + (size_t)col * CP;
    f32x4 c0 = {0.f,0.f,0.f,0.f}, c1 = {0.f,0.f,0.f,0.f}, c2 = {0.f,0.f,0.f,0.f};
    #pragma unroll 4
    for (int s = 0; s < CP / 32; s++) {
        int k = 32 * s;
        FR fsh, fsl, fah, fal;
        fsh.u[0] = *(const ushort4*)(sh + k + o0); fsh.u[1] = *(const ushort4*)(sh + k + o1);
        fsl.u[0] = *(const ushort4*)(sl + k + o0); fsl.u[1] = *(const ushort4*)(sl + k + o1);
        fah.u[0] = *(const ushort4*)(ah + k + o0); fah.u[1] = *(const ushort4*)(ah + k + o1);
        fal.u[0] = *(const ushort4*)(al + k + o0); fal.u[1] = *(const ushort4*)(al + k + o1);
        c0 = __builtin_amdgcn_mfma_f32_16x16x32_bf16(fsh.v, fah.v, c0, 0, 0, 0);
        c1 = __builtin_amdgcn_mfma_f32_16x16x32_bf16(fsl.v, fah.v, c1, 0, 0, 0);
        c2 = __builtin_amdgcn_mfma_f32_16x16x32_bf16(fsh.v, fal.v, c2, 0, 0, 0);
    }
    int valid = (map[col] >= 0);
    #pragma unroll
    for (int r = 0; r < 4; r++) {
        int row = m0 + 4*lg + r;                // C/D: col=lane&15, row=(lane>>4)*4+reg
        float acc = c0[r] + c1[r] + c2[r];
        float v = 0.f;
        if (valid) v = sigm(CT[(size_t)row * TPP + col] + acc);
        __bf16 h = (__bf16)v;
        size_t o = (size_t)row * TPP + col;
        NH[o] = bf2u(h);
        NL[o] = bf2u((__bf16)(v - (float)h));
    }
}

// ---------------- extract default slots ----------------
__global__ void k_out2(const ushort* __restrict__ SH, const ushort* __restrict__ SL,
                       float* __restrict__ out) {
    int idx = threadIdx.x;
    if (idx < NB * NY) {
        int m = idx >> 1, c = idx & 1;
        size_t o = (size_t)m * TPP + c * CP + CP - 1;
        out[idx] = u2f(SH[o]) + u2f(SL[o]);
    }
}

extern "C" void kernel_launch(void* const* d_in, const int* in_sizes, int n_in,
                              void* d_out, int out_size, void* d_ws, size_t ws_size,
                              hipStream_t stream) {
    const float* Xtr    = (const float*)d_in[0];
    const float* Xdef   = (const float*)d_in[1];
    const float* Xq     = (const float*)d_in[2];
    const float* worder = (const float*)d_in[3];
    const float* wbase  = (const float*)d_in[4];
    const int*   ytr    = (const int*)d_in[5];

    const size_t MATP = (size_t)TPP * TPP * 4;     // 6.55 MB
    const size_t VECP = (size_t)NB * TPP * 4;      // 1.31 MB
    const size_t ATB  = (size_t)TPP * CP * 2;      // 1.64 MB
    const size_t SB   = (size_t)NB * TPP * 2;      // 0.655 MB
    auto need = [&](int ps) {
        return (size_t)(8 * 8192) + 2 * MATP + (size_t)ps * 2 * CP * CP * 4
             + 2 * ATB + VECP + 4 * SB + 65536;
    };
    int psplit = 4;
    if (ws_size < need(4)) psplit = 2;
    if (ws_size < need(2)) psplit = 1;
    int kspan = CP / psplit;

    char* ws = (char*)d_ws;
    size_t off = 0;
    auto alloc = [&](size_t bytes) {
        void* r = ws + off;
        off += (bytes + 255) & ~(size_t)255;
        return r;
    };
    float*  p    = (float*)alloc((size_t)TP * 4);
    float*  bl   = (float*)alloc((size_t)TP * 4);
    float*  xsq  = (float*)alloc((size_t)TP * 4);
    int*    map  = (int*)  alloc((size_t)TPP * 4);
    float*  pp   = (float*)alloc((size_t)TPP * 4);
    int*    flag = (int*)  alloc(256);
    float*  Es   = (float*)alloc(MATP);
    float*  Amat = (float*)alloc(MATP);
    float*  P    = (float*)alloc((size_t)psplit * 2 * CP * CP * 4);
    ushort* ATH  = (ushort*)alloc(ATB);
    ushort* ATL  = (ushort*)alloc(ATB);
    float*  CT   = (float*)alloc(VECP);
    ushort* SH0  = (ushort*)alloc(SB);
    ushort* SL0  = (ushort*)alloc(SB);
    ushort* SH1  = (ushort*)alloc(SB);
    ushort* SL1  = (ushort*)alloc(SB);

    k_prep<<<TP, 128, 0, stream>>>(Xtr, Xdef, worder, wbase, p, bl, xsq);
    k_perm<<<1, 1024, 0, stream>>>(ytr, p, map, pp);
    k_es2<<<dim3(TPP / 256, TPP), 256, 0, stream>>>(map, pp, Es);
    k_pblk2<<<dim3(CP / 64, CP / 64, 2 * psplit), 256, 0, stream>>>(Es, P, kspan);
    k_afin2<<<(int)((2 * (size_t)CP * CP) / 256), 256, 0, stream>>>(P, psplit, map, pp, Es, Amat);
    k_absplit<<<dim3(CP / 64, TPP / 64), 256, 0, stream>>>(Amat, ATH, ATL);
    k_cq2<<<dim3(TPP / 256, NB), 256, 0, stream>>>(Xtr, Xdef, Xq, bl, map, CT, SH0, SL0);
    k_probe<<<1, 64, 0, stream>>>(flag);

    ushort *ch = SH0, *cl = SL0, *nh = SH1, *nl = SL1;
    for (int it = 0; it < NITER; it++) {
        k_imfma<<<dim3(TPP / 16, NB / 64), 256, 0, stream>>>(ch, cl, ATH, ATL, CT, map,
                                                             flag, nh, nl);
        ushort* t;
        t = ch; ch = nh; nh = t;
        t = cl; cl = nl; nl = t;
    }
    k_out2<<<1, 512, 0, stream>>>(ch, cl, (float*)d_out);
}

// Round 7
// 451.492 us; speedup vs baseline: 1.7952x; 1.7952x over previous
//
#include <hip/hip_runtime.h>

#define NTRAIN 1024
#define NY 2
#define DDIM 128
#define NB 256
#define NITER 16
#define TT 1026          // NTRAIN + NY
#define TP 1088          // orig-index padding (for p/bl/xsq arrays)
#define CP 640           // class panel size (10*64); holds up to 639 train + 1 default
#define TPP (2*CP)       // 1280 permuted slots
#define SCALE_C 0.25f
#define GAMMA_C 0.05f
#define TAU_C 256.0f     // 2*D
#define IKCH 128         // k-chunk for the MFMA iteration kernel

typedef __attribute__((ext_vector_type(8))) __bf16 bf16x8;
typedef __attribute__((ext_vector_type(4))) float f32x4;
typedef __attribute__((ext_vector_type(8))) unsigned short us8;

union FR { ushort4 u[2]; bf16x8 v; };

__device__ __forceinline__ float sigm(float x) {
    return 1.0f / (1.0f + __expf(-x));
}
__device__ __forceinline__ ushort bf2u(__bf16 b) {
    union { __bf16 b; ushort u; } x; x.b = b; return x.u;
}
__device__ __forceinline__ float u2f(ushort u) {
    union { __bf16 b; ushort u; } x; x.u = u; return (float)x.b;
}

// ---------------- prep: p, base_logit, xsq (orig index space) ----------------
__global__ void k_prep(const float* __restrict__ Xtr, const float* __restrict__ Xdef,
                       const float* __restrict__ worder, const float* __restrict__ wbase,
                       float* __restrict__ p, float* __restrict__ bl,
                       float* __restrict__ xsq) {
    int t = blockIdx.x;        // 0..TP-1
    int tx = threadIdx.x;      // 128 threads
    __shared__ float sp[128], sb[128], ss[128];
    float po = 0.f, bo = 0.f, sq = 0.f;
    if (t < TT) {
        const float* row = (t < NTRAIN) ? (Xtr + (size_t)t * DDIM)
                                        : (Xdef + (size_t)(t - NTRAIN) * DDIM);
        float x = row[tx];
        po = x * worder[tx];
        bo = x * wbase[tx];
        sq = x * x;
    }
    sp[tx] = po; sb[tx] = bo; ss[tx] = sq;
    __syncthreads();
    for (int off = 64; off > 0; off >>= 1) {
        if (tx < off) { sp[tx] += sp[tx+off]; sb[tx] += sb[tx+off]; ss[tx] += ss[tx+off]; }
        __syncthreads();
    }
    if (tx == 0) { p[t] = sp[0]; bl[t] = sb[0]; xsq[t] = ss[0]; }
}

// ---------------- label-sort permutation: map[slot] -> orig index (-1 = pad) ----------------
__global__ void k_perm(const int* __restrict__ ytr, const float* __restrict__ p,
                       int* __restrict__ map, float* __restrict__ pp) {
    __shared__ int ly[NTRAIN];
    int tid = threadIdx.x;                 // 1024 threads
    ly[tid] = ytr[tid];
    for (int a = tid; a < TPP; a += 1024) map[a] = -1;
    __syncthreads();
    int c = ly[tid];
    int rank = 0;
    for (int j = 0; j < NTRAIN; j++) {     // uniform loop, LDS broadcast
        int v = ly[j];
        if (j < tid && v == c) rank++;
    }
    if (rank < CP - 1) map[c * CP + rank] = tid;
    if (tid < NY) map[tid * CP + CP - 1] = NTRAIN + tid;
    __syncthreads();
    for (int a = tid; a < TPP; a += 1024) {
        int m = map[a];
        pp[a] = (m >= 0) ? p[m] : 0.f;
    }
}

// ---------------- Es'[a,b] = sigma(0.25(p_a-p_b))^2 in permuted space ----------------
__global__ void k_es2(const int* __restrict__ map, const float* __restrict__ pp,
                      float* __restrict__ Es) {
    int b = blockIdx.x * 256 + threadIdx.x;   // col slot
    int a = blockIdx.y;                       // row slot
    float v = 0.f;
    int mi = map[a], mj = map[b];
    if (mi >= 0 && mi < NTRAIN && mj >= 0) {
        float e = sigm(SCALE_C * (pp[a] - pp[b]));
        v = e * e;
    }
    Es[(size_t)a * TPP + b] = v;
}

// ---------------- partial blocked product, cross-panel only ----------------
#define KC 16
__global__ __launch_bounds__(256) void k_pblk2(const float* __restrict__ Es,
                                               float* __restrict__ P, int kspan) {
    __shared__ float Wt[KC][64 + 4];
    __shared__ float Et[KC][64 + 4];
    int c  = blockIdx.z & 1;
    int kz = blockIdx.z >> 1;
    int i0 = c * CP + blockIdx.y * 64;
    int j0 = (1 - c) * CP + blockIdx.x * 64;
    int ks = c * CP + kz * kspan, ke = ks + kspan;
    int tid = threadIdx.x;
    int tx = tid & 15, ty = tid >> 4;
    float prod[4][4];
    #pragma unroll
    for (int a = 0; a < 4; a++)
        #pragma unroll
        for (int b = 0; b < 4; b++) prod[a][b] = 1.f;

    for (int k0 = ks; k0 < ke; k0 += KC) {
        __syncthreads();
        #pragma unroll
        for (int e = tid; e < KC * 64; e += 256) {
            int kk = e & 15, ii = e >> 4;
            int gi = i0 + ii, gk = k0 + kk;
            float w = Es[(size_t)gi * TPP + gk];
            if (gi == gk) w = 0.f;
            Wt[kk][ii] = w;
        }
        #pragma unroll
        for (int e = tid; e < KC * 64; e += 256) {
            int jj = e & 63, kk = e >> 6;
            Et[kk][jj] = Es[(size_t)(k0 + kk) * TPP + j0 + jj];
        }
        __syncthreads();
        #pragma unroll
        for (int kk = 0; kk < KC; kk++) {
            float4 wv = *(const float4*)&Wt[kk][ty * 4];
            float4 ev = *(const float4*)&Et[kk][tx * 4];
            float w[4] = {wv.x, wv.y, wv.z, wv.w};
            float e[4] = {ev.x, ev.y, ev.z, ev.w};
            #pragma unroll
            for (int a = 0; a < 4; a++)
                #pragma unroll
                for (int b = 0; b < 4; b++)
                    prod[a][b] *= fmaf(-w[a], e[b], 1.f);
        }
    }
    float* Pz = P + (size_t)blockIdx.z * CP * CP;
    int jjl = blockIdx.x * 64 + tx * 4;
    #pragma unroll
    for (int a = 0; a < 4; a++) {
        int iil = blockIdx.y * 64 + ty * 4 + a;
        *(float4*)&Pz[(size_t)iil * CP + jjl] =
            make_float4(prod[a][0], prod[a][1], prod[a][2], prod[a][3]);
    }
}

// ---------------- combine partials + assemble A' (cross blocks only) ----------------
__global__ void k_afin2(const float* __restrict__ P, int psplit,
                        const int* __restrict__ map, const float* __restrict__ pp,
                        const float* __restrict__ Es, float* __restrict__ A) {
    size_t e = (size_t)blockIdx.x * 256 + threadIdx.x;
    int c = (int)(e / ((size_t)CP * CP));
    int rem = (int)(e % ((size_t)CP * CP));
    int iil = rem / CP, jjl = rem % CP;
    int a = c * CP + iil, b = (1 - c) * CP + jjl;
    float prod = P[(size_t)c * CP * CP + rem];
    for (int kz = 1; kz < psplit; kz++)
        prod *= P[(size_t)(kz * 2 + c) * CP * CP + rem];
    float v = 0.f;
    int mi = map[a], mj = map[b];
    if (mi >= 0 && mj >= 0) {
        float es = Es[(size_t)a * TPP + b];
        float x = SCALE_C * (pp[a] - pp[b]);
        float E = sigm(x);
        float sym = (mi < NTRAIN) ? E * (1.f - E) : 0.f;
        v = -(es * prod + sym);
    }
    A[(size_t)a * TPP + b] = v;
}

// ---------------- AT split: ATh/ATl[n][klocal] (bf16 hi/lo of A[k][n], opposite panel) ----------------
__global__ __launch_bounds__(256) void k_absplit(const float* __restrict__ A,
                                                 ushort* __restrict__ ATH,
                                                 ushort* __restrict__ ATL) {
    __shared__ float t[64][65];
    int n0 = blockIdx.y * 64;
    int d = (n0 >= CP) ? 1 : 0;
    int kg0 = (1 - d) * CP + blockIdx.x * 64;   // global k (opposite panel)
    int kl0 = blockIdx.x * 64;                  // local k in AT row
    int tid = threadIdx.x;
    for (int e = tid; e < 64 * 64; e += 256) {
        int r = e >> 6, c = e & 63;             // c fast -> coalesced A read
        t[r][c] = A[(size_t)(kg0 + r) * TPP + n0 + c];
    }
    __syncthreads();
    for (int e = tid; e < 64 * 64; e += 256) {
        int kk = e & 63, nn = e >> 6;           // kk fast -> coalesced writes
        float x = t[kk][nn];
        __bf16 h = (__bf16)x;
        size_t o = (size_t)(n0 + nn) * CP + kl0 + kk;
        ATH[o] = bf2u(h);
        ATL[o] = bf2u((__bf16)(x - (float)h));
    }
}

// ---------------- CT (f32) + S0 hi/lo bf16, permuted, row-major [NB][TPP] ----------------
__global__ void k_cq2(const float* __restrict__ Xtr, const float* __restrict__ Xdef,
                      const float* __restrict__ Xq, const float* __restrict__ bl,
                      const int* __restrict__ map,
                      float* __restrict__ CT, ushort* __restrict__ SH,
                      ushort* __restrict__ SL) {
    int bq = blockIdx.y;
    int t = blockIdx.x * 256 + threadIdx.x;
    int mi = map[t];
    float cv = 0.f, sv = 0.f;
    if (mi >= 0) {
        const float4* q4 = (const float4*)(Xq + (size_t)bq * DDIM);
        const float* row = (mi < NTRAIN) ? (Xtr + (size_t)mi * DDIM)
                                         : (Xdef + (size_t)(mi - NTRAIN) * DDIM);
        const float4* x4 = (const float4*)row;
        float dot = 0.f, qs = 0.f, xs = 0.f;
        #pragma unroll
        for (int d = 0; d < DDIM / 4; d++) {
            float4 q = q4[d], x = x4[d];
            dot = fmaf(q.x, x.x, fmaf(q.y, x.y, fmaf(q.z, x.z, fmaf(q.w, x.w, dot))));
            qs  = fmaf(q.x, q.x, fmaf(q.y, q.y, fmaf(q.z, q.z, fmaf(q.w, q.w, qs))));
            xs  = fmaf(x.x, x.x, fmaf(x.y, x.y, fmaf(x.z, x.z, fmaf(x.w, x.w, xs))));
        }
        float sq = qs + xs - 2.f * dot;
        float r = sigm(GAMMA_C * (sq - TAU_C));
        cv = bl[mi] - r;
        sv = sigm(bl[mi]);
    }
    size_t o = (size_t)bq * TPP + t;
    CT[o] = cv;
    __bf16 h = (__bf16)sv;
    SH[o] = bf2u(h);
    SL[o] = bf2u((__bf16)(sv - (float)h));
}

// ---------------- MFMA A/B fragment-layout probe (exact-integer self-check) ----------------
__device__ __forceinline__ float Aval(int m, int k) { return (float)((3*m + 7*k) % 13 - 6); }
__device__ __forceinline__ float Bval(int k, int n) { return (float)((5*k + 11*n) % 9 - 4); }

__global__ void k_probe(int* __restrict__ flag) {
    int lane = threadIdx.x;        // 1 wave
    int lg = lane >> 4, li = lane & 15;
    // hypothesis H0 (two-half): k = 4*lg + j (j<4), 16 + 4*lg + (j-4)
    FR fa, fb;
    #pragma unroll
    for (int j = 0; j < 8; j++) {
        int k = (j < 4) ? (4*lg + j) : (16 + 4*lg + (j - 4));
        fa.v[j] = (__bf16)Aval(li, k);
        fb.v[j] = (__bf16)Bval(k, li);
    }
    f32x4 acc = {0.f, 0.f, 0.f, 0.f};
    acc = __builtin_amdgcn_mfma_f32_16x16x32_bf16(fa.v, fb.v, acc, 0, 0, 0);
    int ok = 1;
    #pragma unroll
    for (int r = 0; r < 4; r++) {
        int row = 4*lg + r, col = li;
        float ref = 0.f;
        for (int k = 0; k < 32; k++) ref += Aval(row, k) * Bval(k, col);
        if (acc[r] != ref) ok = 0;
    }
    int allok = __all(ok);
    if (lane == 0) *flag = allok ? 0 : 1;   // 0 -> H0, 1 -> H1 (k = 8*lg + j)
}

// ---------------- one iteration, LDS-staged MFMA: Snew = sigma(CT + S@A') ----------------
// grid (TPP/32, NB/32), 256 thr = 4 waves in 2x2; block tile 32(m) x 32(n), K=640.
__global__ __launch_bounds__(256) void k_imfma2(const ushort* __restrict__ SH,
                                                const ushort* __restrict__ SL,
                                                const ushort* __restrict__ ATH,
                                                const ushort* __restrict__ ATL,
                                                const float* __restrict__ CT,
                                                const int* __restrict__ map,
                                                const int* __restrict__ flag,
                                                ushort* __restrict__ NH,
                                                ushort* __restrict__ NL) {
    __shared__ ushort ShL[32][IKCH + 8];
    __shared__ ushort SlL[32][IKCH + 8];
    __shared__ ushort AhL[32][IKCH + 8];
    __shared__ ushort AlL[32][IKCH + 8];
    int tid = threadIdx.x;
    int n0 = blockIdx.x * 32;
    int m0 = blockIdx.y * 32;
    int kb = (n0 >= CP) ? 0 : CP;              // k over OPPOSITE panel (global slots)
    int wv = tid >> 6, lane = tid & 63;
    int wm = wv >> 1, wn = wv & 1;
    int lg = lane >> 4, li = lane & 15;
    int hyp = *flag;
    int o0 = hyp ? (8*lg)     : (4*lg);
    int o1 = hyp ? (8*lg + 4) : (16 + 4*lg);
    int srow = tid >> 3, sc = tid & 7;         // staging: 8 threads x us8 per row

    f32x4 c0 = {0.f,0.f,0.f,0.f}, c1 = {0.f,0.f,0.f,0.f}, c2 = {0.f,0.f,0.f,0.f};

    for (int k0 = 0; k0 < CP; k0 += IKCH) {
        __syncthreads();
        const ushort* shg = SH + (size_t)(m0 + srow) * TPP + kb + k0;
        const ushort* slg = SL + (size_t)(m0 + srow) * TPP + kb + k0;
        const ushort* ahg = ATH + (size_t)(n0 + srow) * CP + k0;
        const ushort* alg = ATL + (size_t)(n0 + srow) * CP + k0;
        *(us8*)&ShL[srow][sc * 8]       = *(const us8*)(shg + sc * 8);
        *(us8*)&ShL[srow][(sc + 8) * 8] = *(const us8*)(shg + (sc + 8) * 8);
        *(us8*)&SlL[srow][sc * 8]       = *(const us8*)(slg + sc * 8);
        *(us8*)&SlL[srow][(sc + 8) * 8] = *(const us8*)(slg + (sc + 8) * 8);
        *(us8*)&AhL[srow][sc * 8]       = *(const us8*)(ahg + sc * 8);
        *(us8*)&AhL[srow][(sc + 8) * 8] = *(const us8*)(ahg + (sc + 8) * 8);
        *(us8*)&AlL[srow][sc * 8]       = *(const us8*)(alg + sc * 8);
        *(us8*)&AlL[srow][(sc + 8) * 8] = *(const us8*)(alg + (sc + 8) * 8);
        __syncthreads();
        #pragma unroll
        for (int ks = 0; ks < IKCH / 32; ks++) {
            int ka = ks * 32;
            FR fsh, fsl, fah, fal;
            fsh.u[0] = *(const ushort4*)&ShL[wm * 16 + li][ka + o0];
            fsh.u[1] = *(const ushort4*)&ShL[wm * 16 + li][ka + o1];
            fsl.u[0] = *(const ushort4*)&SlL[wm * 16 + li][ka + o0];
            fsl.u[1] = *(const ushort4*)&SlL[wm * 16 + li][ka + o1];
            fah.u[0] = *(const ushort4*)&AhL[wn * 16 + li][ka + o0];
            fah.u[1] = *(const ushort4*)&AhL[wn * 16 + li][ka + o1];
            fal.u[0] = *(const ushort4*)&AlL[wn * 16 + li][ka + o0];
            fal.u[1] = *(const ushort4*)&AlL[wn * 16 + li][ka + o1];
            c0 = __builtin_amdgcn_mfma_f32_16x16x32_bf16(fsh.v, fah.v, c0, 0, 0, 0);
            c1 = __builtin_amdgcn_mfma_f32_16x16x32_bf16(fsl.v, fah.v, c1, 0, 0, 0);
            c2 = __builtin_amdgcn_mfma_f32_16x16x32_bf16(fsh.v, fal.v, c2, 0, 0, 0);
        }
    }
    int col = n0 + wn * 16 + li;
    int valid = (map[col] >= 0);
    #pragma unroll
    for (int r = 0; r < 4; r++) {
        int row = m0 + wm * 16 + 4 * lg + r;   // C/D: col=lane&15, row=(lane>>4)*4+reg
        float acc = c0[r] + c1[r] + c2[r];
        float v = 0.f;
        if (valid) v = sigm(CT[(size_t)row * TPP + col] + acc);
        __bf16 h = (__bf16)v;
        size_t o = (size_t)row * TPP + col;
        NH[o] = bf2u(h);
        NL[o] = bf2u((__bf16)(v - (float)h));
    }
}

// ---------------- extract default slots ----------------
__global__ void k_out2(const ushort* __restrict__ SH, const ushort* __restrict__ SL,
                       float* __restrict__ out) {
    int idx = threadIdx.x;
    if (idx < NB * NY) {
        int m = idx >> 1, c = idx & 1;
        size_t o = (size_t)m * TPP + c * CP + CP - 1;
        out[idx] = u2f(SH[o]) + u2f(SL[o]);
    }
}

extern "C" void kernel_launch(void* const* d_in, const int* in_sizes, int n_in,
                              void* d_out, int out_size, void* d_ws, size_t ws_size,
                              hipStream_t stream) {
    const float* Xtr    = (const float*)d_in[0];
    const float* Xdef   = (const float*)d_in[1];
    const float* Xq     = (const float*)d_in[2];
    const float* worder = (const float*)d_in[3];
    const float* wbase  = (const float*)d_in[4];
    const int*   ytr    = (const int*)d_in[5];

    const size_t MATP = (size_t)TPP * TPP * 4;     // 6.55 MB
    const size_t VECP = (size_t)NB * TPP * 4;      // 1.31 MB
    const size_t ATB  = (size_t)TPP * CP * 2;      // 1.64 MB
    const size_t SB   = (size_t)NB * TPP * 2;      // 0.655 MB
    auto need = [&](int ps) {
        return (size_t)(8 * 8192) + 2 * MATP + (size_t)ps * 2 * CP * CP * 4
             + 2 * ATB + VECP + 4 * SB + 65536;
    };
    int psplit = 8;
    if (ws_size < need(8)) psplit = 4;
    if (ws_size < need(4)) psplit = 2;
    if (ws_size < need(2)) psplit = 1;
    int kspan = CP / psplit;                       // 80 / 160 / 320 (multiples of KC)

    char* ws = (char*)d_ws;
    size_t off = 0;
    auto alloc = [&](size_t bytes) {
        void* r = ws + off;
        off += (bytes + 255) & ~(size_t)255;
        return r;
    };
    float*  p    = (float*)alloc((size_t)TP * 4);
    float*  bl   = (float*)alloc((size_t)TP * 4);
    float*  xsq  = (float*)alloc((size_t)TP * 4);
    int*    map  = (int*)  alloc((size_t)TPP * 4);
    float*  pp   = (float*)alloc((size_t)TPP * 4);
    int*    flag = (int*)  alloc(256);
    float*  Es   = (float*)alloc(MATP);
    float*  Amat = (float*)alloc(MATP);
    float*  P    = (float*)alloc((size_t)psplit * 2 * CP * CP * 4);
    ushort* ATH  = (ushort*)alloc(ATB);
    ushort* ATL  = (ushort*)alloc(ATB);
    float*  CT   = (float*)alloc(VECP);
    ushort* SH0  = (ushort*)alloc(SB);
    ushort* SL0  = (ushort*)alloc(SB);
    ushort* SH1  = (ushort*)alloc(SB);
    ushort* SL1  = (ushort*)alloc(SB);

    k_prep<<<TP, 128, 0, stream>>>(Xtr, Xdef, worder, wbase, p, bl, xsq);
    k_perm<<<1, 1024, 0, stream>>>(ytr, p, map, pp);
    k_es2<<<dim3(TPP / 256, TPP), 256, 0, stream>>>(map, pp, Es);
    k_pblk2<<<dim3(CP / 64, CP / 64, 2 * psplit), 256, 0, stream>>>(Es, P, kspan);
    k_afin2<<<(int)((2 * (size_t)CP * CP) / 256), 256, 0, stream>>>(P, psplit, map, pp, Es, Amat);
    k_absplit<<<dim3(CP / 64, TPP / 64), 256, 0, stream>>>(Amat, ATH, ATL);
    k_cq2<<<dim3(TPP / 256, NB), 256, 0, stream>>>(Xtr, Xdef, Xq, bl, map, CT, SH0, SL0);
    k_probe<<<1, 64, 0, stream>>>(flag);

    ushort *ch = SH0, *cl = SL0, *nh = SH1, *nl = SL1;
    for (int it = 0; it < NITER; it++) {
        k_imfma2<<<dim3(TPP / 32, NB / 32), 256, 0, stream>>>(ch, cl, ATH, ATL, CT, map,
                                                              flag, nh, nl);
        ushort* t;
        t = ch; ch = nh; nh = t;
        t = cl; cl = nl; nl = t;
    }
    k_out2<<<1, 512, 0, stream>>>(ch, cl, (float*)d_out);
}

// Round 8
// 325.114 us; speedup vs baseline: 2.4930x; 1.3887x over previous
//
#include <hip/hip_runtime.h>

#define NTRAIN 1024
#define NY 2
#define DDIM 128
#define NB 256
#define NITER 16
#define TT 1026          // NTRAIN + NY
#define TP 1088          // orig-index padding (for p/bl/xsq arrays)
#define CP 640           // class panel size (10*64); holds up to 639 train + 1 default
#define TPP (2*CP)       // 1280 permuted slots
#define SCALE_C 0.25f
#define GAMMA_C 0.05f
#define TAU_C 256.0f     // 2*D
#define IKCH 128         // k-chunk for the MFMA iteration kernel

typedef __attribute__((ext_vector_type(8))) __bf16 bf16x8;
typedef __attribute__((ext_vector_type(4))) float f32x4;
typedef __attribute__((ext_vector_type(8))) unsigned short us8;

union FR { ushort4 u[2]; bf16x8 v; };

__device__ __forceinline__ float sigm(float x) {
    return 1.0f / (1.0f + __expf(-x));
}
__device__ __forceinline__ ushort bf2u(__bf16 b) {
    union { __bf16 b; ushort u; } x; x.b = b; return x.u;
}

// ---------------- prep: p, base_logit, xsq (orig index space) ----------------
__global__ void k_prep(const float* __restrict__ Xtr, const float* __restrict__ Xdef,
                       const float* __restrict__ worder, const float* __restrict__ wbase,
                       float* __restrict__ p, float* __restrict__ bl,
                       float* __restrict__ xsq) {
    int t = blockIdx.x;        // 0..TP-1
    int tx = threadIdx.x;      // 128 threads
    __shared__ float sp[128], sb[128], ss[128];
    float po = 0.f, bo = 0.f, sq = 0.f;
    if (t < TT) {
        const float* row = (t < NTRAIN) ? (Xtr + (size_t)t * DDIM)
                                        : (Xdef + (size_t)(t - NTRAIN) * DDIM);
        float x = row[tx];
        po = x * worder[tx];
        bo = x * wbase[tx];
        sq = x * x;
    }
    sp[tx] = po; sb[tx] = bo; ss[tx] = sq;
    __syncthreads();
    for (int off = 64; off > 0; off >>= 1) {
        if (tx < off) { sp[tx] += sp[tx+off]; sb[tx] += sb[tx+off]; ss[tx] += ss[tx+off]; }
        __syncthreads();
    }
    if (tx == 0) { p[t] = sp[0]; bl[t] = sb[0]; xsq[t] = ss[0]; }
}

// ---------------- label-sort permutation via 64-bit ballot (Y==2) ----------------
// map[slot] -> orig index (-1 = pad); panel c holds train by rank + default at c*CP+CP-1.
__global__ void k_perm2(const int* __restrict__ ytr, const float* __restrict__ p,
                        int* __restrict__ map, float* __restrict__ pp) {
    __shared__ int cnt1[16];
    int tid = threadIdx.x;                 // 1024 threads = 16 waves
    int w = tid >> 6, lane = tid & 63;
    for (int a = tid; a < TPP; a += 1024) map[a] = -1;
    int y = ytr[tid];
    unsigned long long b1 = __ballot(y == 1);
    if (lane == 0) cnt1[w] = (int)__popcll(b1);
    __syncthreads();
    int pref1 = 0;
    #pragma unroll
    for (int ww = 0; ww < 16; ww++) pref1 += (ww < w) ? cnt1[ww] : 0;
    int pref0 = w * 64 - pref1;
    unsigned long long mlt = ((unsigned long long)1 << lane) - 1ull;
    int rank = y ? (pref1 + (int)__popcll(b1 & mlt))
                 : (pref0 + (int)__popcll((~b1) & mlt));
    if (rank < CP - 1) map[y * CP + rank] = tid;
    if (tid < NY) map[tid * CP + CP - 1] = NTRAIN + tid;
    __syncthreads();
    for (int a = tid; a < TPP; a += 1024) {
        int m = map[a];
        pp[a] = (m >= 0) ? p[m] : 0.f;
    }
}

// ---------------- Es'[a,b] = sigma(0.25(p_a-p_b))^2 in permuted space ----------------
__global__ void k_es2(const int* __restrict__ map, const float* __restrict__ pp,
                      float* __restrict__ Es) {
    int b = blockIdx.x * 256 + threadIdx.x;   // col slot
    int a = blockIdx.y;                       // row slot
    float v = 0.f;
    int mi = map[a], mj = map[b];
    if (mi >= 0 && mi < NTRAIN && mj >= 0) {
        float e = sigm(SCALE_C * (pp[a] - pp[b]));
        v = e * e;
    }
    Es[(size_t)a * TPP + b] = v;
}

// ---------------- partial blocked product, cross-panel only ----------------
#define KC 16
__global__ __launch_bounds__(256) void k_pblk2(const float* __restrict__ Es,
                                               float* __restrict__ P, int kspan) {
    __shared__ float Wt[KC][64 + 4];
    __shared__ float Et[KC][64 + 4];
    int c  = blockIdx.z & 1;
    int kz = blockIdx.z >> 1;
    int i0 = c * CP + blockIdx.y * 64;
    int j0 = (1 - c) * CP + blockIdx.x * 64;
    int ks = c * CP + kz * kspan, ke = ks + kspan;
    int tid = threadIdx.x;
    int tx = tid & 15, ty = tid >> 4;
    float prod[4][4];
    #pragma unroll
    for (int a = 0; a < 4; a++)
        #pragma unroll
        for (int b = 0; b < 4; b++) prod[a][b] = 1.f;

    for (int k0 = ks; k0 < ke; k0 += KC) {
        __syncthreads();
        #pragma unroll
        for (int e = tid; e < KC * 64; e += 256) {
            int kk = e & 15, ii = e >> 4;
            int gi = i0 + ii, gk = k0 + kk;
            float w = Es[(size_t)gi * TPP + gk];
            if (gi == gk) w = 0.f;
            Wt[kk][ii] = w;
        }
        #pragma unroll
        for (int e = tid; e < KC * 64; e += 256) {
            int jj = e & 63, kk = e >> 6;
            Et[kk][jj] = Es[(size_t)(k0 + kk) * TPP + j0 + jj];
        }
        __syncthreads();
        #pragma unroll
        for (int kk = 0; kk < KC; kk++) {
            float4 wv = *(const float4*)&Wt[kk][ty * 4];
            float4 ev = *(const float4*)&Et[kk][tx * 4];
            float w[4] = {wv.x, wv.y, wv.z, wv.w};
            float e[4] = {ev.x, ev.y, ev.z, ev.w};
            #pragma unroll
            for (int a = 0; a < 4; a++)
                #pragma unroll
                for (int b = 0; b < 4; b++)
                    prod[a][b] *= fmaf(-w[a], e[b], 1.f);
        }
    }
    float* Pz = P + (size_t)blockIdx.z * CP * CP;
    int jjl = blockIdx.x * 64 + tx * 4;
    #pragma unroll
    for (int a = 0; a < 4; a++) {
        int iil = blockIdx.y * 64 + ty * 4 + a;
        *(float4*)&Pz[(size_t)iil * CP + jjl] =
            make_float4(prod[a][0], prod[a][1], prod[a][2], prod[a][3]);
    }
}

// ---------------- combine partials + assemble A' (cross blocks only) ----------------
__global__ void k_afin2(const float* __restrict__ P, int psplit,
                        const int* __restrict__ map, const float* __restrict__ pp,
                        const float* __restrict__ Es, float* __restrict__ A) {
    size_t e = (size_t)blockIdx.x * 256 + threadIdx.x;
    int c = (int)(e / ((size_t)CP * CP));
    int rem = (int)(e % ((size_t)CP * CP));
    int iil = rem / CP, jjl = rem % CP;
    int a = c * CP + iil, b = (1 - c) * CP + jjl;
    float prod = P[(size_t)c * CP * CP + rem];
    for (int kz = 1; kz < psplit; kz++)
        prod *= P[(size_t)(kz * 2 + c) * CP * CP + rem];
    float v = 0.f;
    int mi = map[a], mj = map[b];
    if (mi >= 0 && mj >= 0) {
        float es = Es[(size_t)a * TPP + b];
        float x = SCALE_C * (pp[a] - pp[b]);
        float E = sigm(x);
        float sym = (mi < NTRAIN) ? E * (1.f - E) : 0.f;
        v = -(es * prod + sym);
    }
    A[(size_t)a * TPP + b] = v;
}

// ---------------- AT split: ATh/ATl[n][klocal] (bf16 hi/lo of A[k][n], opposite panel) ----------------
__global__ __launch_bounds__(256) void k_absplit(const float* __restrict__ A,
                                                 ushort* __restrict__ ATH,
                                                 ushort* __restrict__ ATL) {
    __shared__ float t[64][65];
    int n0 = blockIdx.y * 64;
    int d = (n0 >= CP) ? 1 : 0;
    int kg0 = (1 - d) * CP + blockIdx.x * 64;   // global k (opposite panel)
    int kl0 = blockIdx.x * 64;                  // local k in AT row
    int tid = threadIdx.x;
    for (int e = tid; e < 64 * 64; e += 256) {
        int r = e >> 6, c = e & 63;             // c fast -> coalesced A read
        t[r][c] = A[(size_t)(kg0 + r) * TPP + n0 + c];
    }
    __syncthreads();
    for (int e = tid; e < 64 * 64; e += 256) {
        int kk = e & 63, nn = e >> 6;           // kk fast -> coalesced writes
        float x = t[kk][nn];
        __bf16 h = (__bf16)x;
        size_t o = (size_t)(n0 + nn) * CP + kl0 + kk;
        ATH[o] = bf2u(h);
        ATL[o] = bf2u((__bf16)(x - (float)h));
    }
}

// ---------------- CT (f32) + S0 hi/lo bf16, permuted, row-major [NB][TPP] ----------------
__global__ void k_cq2(const float* __restrict__ Xtr, const float* __restrict__ Xdef,
                      const float* __restrict__ Xq, const float* __restrict__ bl,
                      const int* __restrict__ map,
                      float* __restrict__ CT, ushort* __restrict__ SH,
                      ushort* __restrict__ SL) {
    int bq = blockIdx.y;
    int t = blockIdx.x * 256 + threadIdx.x;
    int mi = map[t];
    float cv = 0.f, sv = 0.f;
    if (mi >= 0) {
        const float4* q4 = (const float4*)(Xq + (size_t)bq * DDIM);
        const float* row = (mi < NTRAIN) ? (Xtr + (size_t)mi * DDIM)
                                         : (Xdef + (size_t)(mi - NTRAIN) * DDIM);
        const float4* x4 = (const float4*)row;
        float dot = 0.f, qs = 0.f, xs = 0.f;
        #pragma unroll
        for (int d = 0; d < DDIM / 4; d++) {
            float4 q = q4[d], x = x4[d];
            dot = fmaf(q.x, x.x, fmaf(q.y, x.y, fmaf(q.z, x.z, fmaf(q.w, x.w, dot))));
            qs  = fmaf(q.x, q.x, fmaf(q.y, q.y, fmaf(q.z, q.z, fmaf(q.w, q.w, qs))));
            xs  = fmaf(x.x, x.x, fmaf(x.y, x.y, fmaf(x.z, x.z, fmaf(x.w, x.w, xs))));
        }
        float sq = qs + xs - 2.f * dot;
        float r = sigm(GAMMA_C * (sq - TAU_C));
        cv = bl[mi] - r;
        sv = sigm(bl[mi]);
    }
    size_t o = (size_t)bq * TPP + t;
    CT[o] = cv;
    __bf16 h = (__bf16)sv;
    SH[o] = bf2u(h);
    SL[o] = bf2u((__bf16)(sv - (float)h));
}

// ---------------- MFMA A/B fragment-layout probe (exact-integer self-check) ----------------
__device__ __forceinline__ float Aval(int m, int k) { return (float)((3*m + 7*k) % 13 - 6); }
__device__ __forceinline__ float Bval(int k, int n) { return (float)((5*k + 11*n) % 9 - 4); }

__global__ void k_probe(int* __restrict__ flag) {
    int lane = threadIdx.x;        // 1 wave
    int lg = lane >> 4, li = lane & 15;
    // hypothesis H0 (two-half): k = 4*lg + j (j<4), 16 + 4*lg + (j-4)
    FR fa, fb;
    #pragma unroll
    for (int j = 0; j < 8; j++) {
        int k = (j < 4) ? (4*lg + j) : (16 + 4*lg + (j - 4));
        fa.v[j] = (__bf16)Aval(li, k);
        fb.v[j] = (__bf16)Bval(k, li);
    }
    f32x4 acc = {0.f, 0.f, 0.f, 0.f};
    acc = __builtin_amdgcn_mfma_f32_16x16x32_bf16(fa.v, fb.v, acc, 0, 0, 0);
    int ok = 1;
    #pragma unroll
    for (int r = 0; r < 4; r++) {
        int row = 4*lg + r, col = li;
        float ref = 0.f;
        for (int k = 0; k < 32; k++) ref += Aval(row, k) * Bval(k, col);
        if (acc[r] != ref) ok = 0;
    }
    int allok = __all(ok);
    if (lane == 0) *flag = allok ? 0 : 1;   // 0 -> H0, 1 -> H1 (k = 8*lg + j)
}

// ---------------- one iteration, LDS-staged MFMA with register prefetch ----------------
// grid (TPP/32, NB/32), 256 thr = 4 waves in 2x2; block tile 32(m) x 32(n), K=640.
// T14 async-stage: chunk t+1's global loads issue before chunk t's MFMAs.
__global__ __launch_bounds__(256) void k_imfma3(const ushort* __restrict__ SH,
                                                const ushort* __restrict__ SL,
                                                const ushort* __restrict__ ATH,
                                                const ushort* __restrict__ ATL,
                                                const float* __restrict__ CT,
                                                const int* __restrict__ map,
                                                const int* __restrict__ flag,
                                                ushort* __restrict__ NH,
                                                ushort* __restrict__ NL,
                                                float* __restrict__ out, int last) {
    __shared__ ushort ShL[32][IKCH + 8];
    __shared__ ushort SlL[32][IKCH + 8];
    __shared__ ushort AhL[32][IKCH + 8];
    __shared__ ushort AlL[32][IKCH + 8];
    int tid = threadIdx.x;
    int n0 = blockIdx.x * 32;
    int m0 = blockIdx.y * 32;
    int kb = (n0 >= CP) ? 0 : CP;              // k over OPPOSITE panel (global slots)
    int wv = tid >> 6, lane = tid & 63;
    int wm = wv >> 1, wn = wv & 1;
    int lg = lane >> 4, li = lane & 15;
    int hyp = *flag;
    int o0 = hyp ? (8*lg)     : (4*lg);
    int o1 = hyp ? (8*lg + 4) : (16 + 4*lg);
    int srow = tid >> 3, sc = tid & 7;         // staging: 8 threads x 2 us8 per row

    const ushort* shg = SH + (size_t)(m0 + srow) * TPP + kb;
    const ushort* slg = SL + (size_t)(m0 + srow) * TPP + kb;
    const ushort* ahg = ATH + (size_t)(n0 + srow) * CP;
    const ushort* alg = ATL + (size_t)(n0 + srow) * CP;

    f32x4 c0 = {0.f,0.f,0.f,0.f}, c1 = {0.f,0.f,0.f,0.f}, c2 = {0.f,0.f,0.f,0.f};

    us8 buf[8];
    #define ISSUE(dst, k0)                                            \
        dst[0] = *(const us8*)(shg + (k0) + sc * 8);                  \
        dst[1] = *(const us8*)(shg + (k0) + (sc + 8) * 8);            \
        dst[2] = *(const us8*)(slg + (k0) + sc * 8);                  \
        dst[3] = *(const us8*)(slg + (k0) + (sc + 8) * 8);            \
        dst[4] = *(const us8*)(ahg + (k0) + sc * 8);                  \
        dst[5] = *(const us8*)(ahg + (k0) + (sc + 8) * 8);            \
        dst[6] = *(const us8*)(alg + (k0) + sc * 8);                  \
        dst[7] = *(const us8*)(alg + (k0) + (sc + 8) * 8);

    ISSUE(buf, 0)

    #pragma unroll
    for (int ci = 0; ci < CP / IKCH; ci++) {
        __syncthreads();                       // previous chunk's LDS reads done
        *(us8*)&ShL[srow][sc * 8]       = buf[0];
        *(us8*)&ShL[srow][(sc + 8) * 8] = buf[1];
        *(us8*)&SlL[srow][sc * 8]       = buf[2];
        *(us8*)&SlL[srow][(sc + 8) * 8] = buf[3];
        *(us8*)&AhL[srow][sc * 8]       = buf[4];
        *(us8*)&AhL[srow][(sc + 8) * 8] = buf[5];
        *(us8*)&AlL[srow][sc * 8]       = buf[6];
        *(us8*)&AlL[srow][(sc + 8) * 8] = buf[7];
        __syncthreads();
        us8 nbuf[8];
        if (ci + 1 < CP / IKCH) { ISSUE(nbuf, (ci + 1) * IKCH) }   // fly under MFMAs
        #pragma unroll
        for (int ks = 0; ks < IKCH / 32; ks++) {
            int ka = ks * 32;
            FR fsh, fsl, fah, fal;
            fsh.u[0] = *(const ushort4*)&ShL[wm * 16 + li][ka + o0];
            fsh.u[1] = *(const ushort4*)&ShL[wm * 16 + li][ka + o1];
            fsl.u[0] = *(const ushort4*)&SlL[wm * 16 + li][ka + o0];
            fsl.u[1] = *(const ushort4*)&SlL[wm * 16 + li][ka + o1];
            fah.u[0] = *(const ushort4*)&AhL[wn * 16 + li][ka + o0];
            fah.u[1] = *(const ushort4*)&AhL[wn * 16 + li][ka + o1];
            fal.u[0] = *(const ushort4*)&AlL[wn * 16 + li][ka + o0];
            fal.u[1] = *(const ushort4*)&AlL[wn * 16 + li][ka + o1];
            c0 = __builtin_amdgcn_mfma_f32_16x16x32_bf16(fsh.v, fah.v, c0, 0, 0, 0);
            c1 = __builtin_amdgcn_mfma_f32_16x16x32_bf16(fsl.v, fah.v, c1, 0, 0, 0);
            c2 = __builtin_amdgcn_mfma_f32_16x16x32_bf16(fsh.v, fal.v, c2, 0, 0, 0);
        }
        if (ci + 1 < CP / IKCH) {
            #pragma unroll
            for (int q = 0; q < 8; q++) buf[q] = nbuf[q];
        }
    }
    #undef ISSUE

    int col = n0 + wn * 16 + li;
    int valid = (map[col] >= 0);
    #pragma unroll
    for (int r = 0; r < 4; r++) {
        int row = m0 + wm * 16 + 4 * lg + r;   // C/D: col=lane&15, row=(lane>>4)*4+reg
        float acc = c0[r] + c1[r] + c2[r];
        float v = 0.f;
        if (valid) v = sigm(CT[(size_t)row * TPP + col] + acc);
        __bf16 h = (__bf16)v;
        size_t o = (size_t)row * TPP + col;
        NH[o] = bf2u(h);
        NL[o] = bf2u((__bf16)(v - (float)h));
        if (last && (col == CP - 1 || col == TPP - 1)) {
            int cc = (col == CP - 1) ? 0 : 1;
            out[row * NY + cc] = v;            // full-precision f32 output
        }
    }
}

extern "C" void kernel_launch(void* const* d_in, const int* in_sizes, int n_in,
                              void* d_out, int out_size, void* d_ws, size_t ws_size,
                              hipStream_t stream) {
    const float* Xtr    = (const float*)d_in[0];
    const float* Xdef   = (const float*)d_in[1];
    const float* Xq     = (const float*)d_in[2];
    const float* worder = (const float*)d_in[3];
    const float* wbase  = (const float*)d_in[4];
    const int*   ytr    = (const int*)d_in[5];

    const size_t MATP = (size_t)TPP * TPP * 4;     // 6.55 MB
    const size_t VECP = (size_t)NB * TPP * 4;      // 1.31 MB
    const size_t ATB  = (size_t)TPP * CP * 2;      // 1.64 MB
    const size_t SB   = (size_t)NB * TPP * 2;      // 0.655 MB
    auto need = [&](int ps) {
        return (size_t)(8 * 8192) + 2 * MATP + (size_t)ps * 2 * CP * CP * 4
             + 2 * ATB + VECP + 4 * SB + 65536;
    };
    int psplit = 8;
    if (ws_size < need(8)) psplit = 4;
    if (ws_size < need(4)) psplit = 2;
    if (ws_size < need(2)) psplit = 1;
    int kspan = CP / psplit;                       // 80 / 160 / 320 (multiples of KC)

    char* ws = (char*)d_ws;
    size_t off = 0;
    auto alloc = [&](size_t bytes) {
        void* r = ws + off;
        off += (bytes + 255) & ~(size_t)255;
        return r;
    };
    float*  p    = (float*)alloc((size_t)TP * 4);
    float*  bl   = (float*)alloc((size_t)TP * 4);
    float*  xsq  = (float*)alloc((size_t)TP * 4);
    int*    map  = (int*)  alloc((size_t)TPP * 4);
    float*  pp   = (float*)alloc((size_t)TPP * 4);
    int*    flag = (int*)  alloc(256);
    float*  Es   = (float*)alloc(MATP);
    float*  Amat = (float*)alloc(MATP);
    float*  P    = (float*)alloc((size_t)psplit * 2 * CP * CP * 4);
    ushort* ATH  = (ushort*)alloc(ATB);
    ushort* ATL  = (ushort*)alloc(ATB);
    float*  CT   = (float*)alloc(VECP);
    ushort* SH0  = (ushort*)alloc(SB);
    ushort* SL0  = (ushort*)alloc(SB);
    ushort* SH1  = (ushort*)alloc(SB);
    ushort* SL1  = (ushort*)alloc(SB);

    k_prep<<<TP, 128, 0, stream>>>(Xtr, Xdef, worder, wbase, p, bl, xsq);
    k_perm2<<<1, 1024, 0, stream>>>(ytr, p, map, pp);
    k_es2<<<dim3(TPP / 256, TPP), 256, 0, stream>>>(map, pp, Es);
    k_pblk2<<<dim3(CP / 64, CP / 64, 2 * psplit), 256, 0, stream>>>(Es, P, kspan);
    k_afin2<<<(int)((2 * (size_t)CP * CP) / 256), 256, 0, stream>>>(P, psplit, map, pp, Es, Amat);
    k_absplit<<<dim3(CP / 64, TPP / 64), 256, 0, stream>>>(Amat, ATH, ATL);
    k_cq2<<<dim3(TPP / 256, NB), 256, 0, stream>>>(Xtr, Xdef, Xq, bl, map, CT, SH0, SL0);
    k_probe<<<1, 64, 0, stream>>>(flag);

    ushort *ch = SH0, *cl = SL0, *nh = SH1, *nl = SL1;
    for (int it = 0; it < NITER; it++) {
        k_imfma3<<<dim3(TPP / 32, NB / 32), 256, 0, stream>>>(ch, cl, ATH, ATL, CT, map,
                                                              flag, nh, nl,
                                                              (float*)d_out,
                                                              it == NITER - 1 ? 1 : 0);
        ushort* t;
        t = ch; ch = nh; nh = t;
        t = cl; cl = nl; nl = t;
    }
}

// Round 9
// 288.544 us; speedup vs baseline: 2.8089x; 1.1267x over previous
//
#include <hip/hip_runtime.h>

#define NTRAIN 1024
#define NY 2
#define DDIM 128
#define NB 256
#define NITER 16
#define TT 1026          // NTRAIN + NY
#define TP 1088          // orig-index padding (for p/bl/xsq arrays)
#define CP 640           // class panel size (10*64); holds up to 639 train + 1 default
#define TPP (2*CP)       // 1280 permuted slots
#define SCALE_C 0.25f
#define GAMMA_C 0.05f
#define TAU_C 256.0f     // 2*D
#define IKCH 128         // k-chunk for the MFMA iteration kernel

typedef _Float16 __attribute__((ext_vector_type(8))) f16x8;
typedef __attribute__((ext_vector_type(4))) float f32x4;
typedef __attribute__((ext_vector_type(8))) unsigned short us8;

union FR16 { ushort4 u[2]; f16x8 v; };

__device__ __forceinline__ float sigm(float x) {
    return 1.0f / (1.0f + __expf(-x));
}
__device__ __forceinline__ ushort f2u16(_Float16 h) {
    union { _Float16 h; ushort u; } x; x.h = h; return x.u;
}

// ---------------- prep: p, base_logit, xsq (orig index space) ----------------
__global__ void k_prep(const float* __restrict__ Xtr, const float* __restrict__ Xdef,
                       const float* __restrict__ worder, const float* __restrict__ wbase,
                       float* __restrict__ p, float* __restrict__ bl,
                       float* __restrict__ xsq) {
    int t = blockIdx.x;        // 0..TP-1
    int tx = threadIdx.x;      // 128 threads
    __shared__ float sp[128], sb[128], ss[128];
    float po = 0.f, bo = 0.f, sq = 0.f;
    if (t < TT) {
        const float* row = (t < NTRAIN) ? (Xtr + (size_t)t * DDIM)
                                        : (Xdef + (size_t)(t - NTRAIN) * DDIM);
        float x = row[tx];
        po = x * worder[tx];
        bo = x * wbase[tx];
        sq = x * x;
    }
    sp[tx] = po; sb[tx] = bo; ss[tx] = sq;
    __syncthreads();
    for (int off = 64; off > 0; off >>= 1) {
        if (tx < off) { sp[tx] += sp[tx+off]; sb[tx] += sb[tx+off]; ss[tx] += ss[tx+off]; }
        __syncthreads();
    }
    if (tx == 0) { p[t] = sp[0]; bl[t] = sb[0]; xsq[t] = ss[0]; }
}

// ---------------- label-sort permutation via 64-bit ballot (Y==2) ----------------
__global__ void k_perm2(const int* __restrict__ ytr, const float* __restrict__ p,
                        int* __restrict__ map, float* __restrict__ pp) {
    __shared__ int cnt1[16];
    int tid = threadIdx.x;                 // 1024 threads = 16 waves
    int w = tid >> 6, lane = tid & 63;
    for (int a = tid; a < TPP; a += 1024) map[a] = -1;
    int y = ytr[tid];
    unsigned long long b1 = __ballot(y == 1);
    if (lane == 0) cnt1[w] = (int)__popcll(b1);
    __syncthreads();
    int pref1 = 0;
    #pragma unroll
    for (int ww = 0; ww < 16; ww++) pref1 += (ww < w) ? cnt1[ww] : 0;
    int pref0 = w * 64 - pref1;
    unsigned long long mlt = ((unsigned long long)1 << lane) - 1ull;
    int rank = y ? (pref1 + (int)__popcll(b1 & mlt))
                 : (pref0 + (int)__popcll((~b1) & mlt));
    if (rank < CP - 1) map[y * CP + rank] = tid;
    if (tid < NY) map[tid * CP + CP - 1] = NTRAIN + tid;
    __syncthreads();
    for (int a = tid; a < TPP; a += 1024) {
        int m = map[a];
        pp[a] = (m >= 0) ? p[m] : 0.f;
    }
}

// ---------------- Es'[a,b] = sigma(0.25(p_a-p_b))^2 in permuted space ----------------
__global__ void k_es2(const int* __restrict__ map, const float* __restrict__ pp,
                      float* __restrict__ Es) {
    int b = blockIdx.x * 256 + threadIdx.x;   // col slot
    int a = blockIdx.y;                       // row slot
    float v = 0.f;
    int mi = map[a], mj = map[b];
    if (mi >= 0 && mi < NTRAIN && mj >= 0) {
        float e = sigm(SCALE_C * (pp[a] - pp[b]));
        v = e * e;
    }
    Es[(size_t)a * TPP + b] = v;
}

// ---------------- partial blocked product, cross-panel only ----------------
#define KC 16
__global__ __launch_bounds__(256) void k_pblk2(const float* __restrict__ Es,
                                               float* __restrict__ P, int kspan) {
    __shared__ float Wt[KC][64 + 4];
    __shared__ float Et[KC][64 + 4];
    int c  = blockIdx.z & 1;
    int kz = blockIdx.z >> 1;
    int i0 = c * CP + blockIdx.y * 64;
    int j0 = (1 - c) * CP + blockIdx.x * 64;
    int ks = c * CP + kz * kspan, ke = ks + kspan;
    int tid = threadIdx.x;
    int tx = tid & 15, ty = tid >> 4;
    float prod[4][4];
    #pragma unroll
    for (int a = 0; a < 4; a++)
        #pragma unroll
        for (int b = 0; b < 4; b++) prod[a][b] = 1.f;

    for (int k0 = ks; k0 < ke; k0 += KC) {
        __syncthreads();
        #pragma unroll
        for (int e = tid; e < KC * 64; e += 256) {
            int kk = e & 15, ii = e >> 4;
            int gi = i0 + ii, gk = k0 + kk;
            float w = Es[(size_t)gi * TPP + gk];
            if (gi == gk) w = 0.f;
            Wt[kk][ii] = w;
        }
        #pragma unroll
        for (int e = tid; e < KC * 64; e += 256) {
            int jj = e & 63, kk = e >> 6;
            Et[kk][jj] = Es[(size_t)(k0 + kk) * TPP + j0 + jj];
        }
        __syncthreads();
        #pragma unroll
        for (int kk = 0; kk < KC; kk++) {
            float4 wv = *(const float4*)&Wt[kk][ty * 4];
            float4 ev = *(const float4*)&Et[kk][tx * 4];
            float w[4] = {wv.x, wv.y, wv.z, wv.w};
            float e[4] = {ev.x, ev.y, ev.z, ev.w};
            #pragma unroll
            for (int a = 0; a < 4; a++)
                #pragma unroll
                for (int b = 0; b < 4; b++)
                    prod[a][b] *= fmaf(-w[a], e[b], 1.f);
        }
    }
    float* Pz = P + (size_t)blockIdx.z * CP * CP;
    int jjl = blockIdx.x * 64 + tx * 4;
    #pragma unroll
    for (int a = 0; a < 4; a++) {
        int iil = blockIdx.y * 64 + ty * 4 + a;
        *(float4*)&Pz[(size_t)iil * CP + jjl] =
            make_float4(prod[a][0], prod[a][1], prod[a][2], prod[a][3]);
    }
}

// ---------------- combine partials + assemble A' + write transposed fp16 ATF ----------------
// ATF[n][kl] = fp16(A'[kglobal][n]), kglobal = opposite-panel slot of n's panel.
// grid (CP/64 kl-tiles, TPP/64 n-tiles), 256 threads; LDS transpose for coalesced writes.
__global__ __launch_bounds__(256) void k_afin2T(const float* __restrict__ P, int psplit,
                                                const int* __restrict__ map,
                                                const float* __restrict__ pp,
                                                const float* __restrict__ Es,
                                                ushort* __restrict__ ATF) {
    __shared__ float t[64][65];
    int n0 = blockIdx.y * 64;
    int d = (n0 >= CP) ? 1 : 0;    // panel of n (target col)
    int c = 1 - d;                 // panel of k (attacker row)
    int kl0 = blockIdx.x * 64;
    int tid = threadIdx.x;
    for (int e = tid; e < 64 * 64; e += 256) {
        int r = e >> 6, col = e & 63;            // col fast -> coalesced P/Es reads
        int iil = kl0 + r;
        int jjl = n0 - d * CP + col;             // local col within P slab
        size_t rem = (size_t)iil * CP + jjl;
        float prod = P[(size_t)c * CP * CP + rem];
        for (int kz = 1; kz < psplit; kz++)
            prod *= P[(size_t)(kz * 2 + c) * CP * CP + rem];
        int a = c * CP + iil, b = n0 + col;
        float v = 0.f;
        int mi = map[a], mj = map[b];
        if (mi >= 0 && mj >= 0) {
            float es = Es[(size_t)a * TPP + b];
            float x = SCALE_C * (pp[a] - pp[b]);
            float E = sigm(x);
            float sym = (mi < NTRAIN) ? E * (1.f - E) : 0.f;
            v = -(es * prod + sym);
        }
        t[r][col] = v;
    }
    __syncthreads();
    for (int e = tid; e < 64 * 64; e += 256) {
        int kk = e & 63, nn = e >> 6;            // kk fast -> coalesced ushort writes
        ATF[(size_t)(n0 + nn) * CP + kl0 + kk] = f2u16((_Float16)t[kk][nn]);
    }
}

// ---------------- CT (f32) + S0 fp16, permuted, row-major [NB][TPP] ----------------
__global__ void k_cq2(const float* __restrict__ Xtr, const float* __restrict__ Xdef,
                      const float* __restrict__ Xq, const float* __restrict__ bl,
                      const int* __restrict__ map,
                      float* __restrict__ CT, ushort* __restrict__ SF) {
    int bq = blockIdx.y;
    int t = blockIdx.x * 256 + threadIdx.x;
    int mi = map[t];
    float cv = 0.f, sv = 0.f;
    if (mi >= 0) {
        const float4* q4 = (const float4*)(Xq + (size_t)bq * DDIM);
        const float* row = (mi < NTRAIN) ? (Xtr + (size_t)mi * DDIM)
                                         : (Xdef + (size_t)(mi - NTRAIN) * DDIM);
        const float4* x4 = (const float4*)row;
        float dot = 0.f, qs = 0.f, xs = 0.f;
        #pragma unroll
        for (int d = 0; d < DDIM / 4; d++) {
            float4 q = q4[d], x = x4[d];
            dot = fmaf(q.x, x.x, fmaf(q.y, x.y, fmaf(q.z, x.z, fmaf(q.w, x.w, dot))));
            qs  = fmaf(q.x, q.x, fmaf(q.y, q.y, fmaf(q.z, q.z, fmaf(q.w, q.w, qs))));
            xs  = fmaf(x.x, x.x, fmaf(x.y, x.y, fmaf(x.z, x.z, fmaf(x.w, x.w, xs))));
        }
        float sq = qs + xs - 2.f * dot;
        float r = sigm(GAMMA_C * (sq - TAU_C));
        cv = bl[mi] - r;
        sv = sigm(bl[mi]);
    }
    size_t o = (size_t)bq * TPP + t;
    CT[o] = cv;
    SF[o] = f2u16((_Float16)sv);
}

// ---------------- MFMA A/B fragment-layout probe (exact-integer, f16) ----------------
__device__ __forceinline__ float Aval(int m, int k) { return (float)((3*m + 7*k) % 13 - 6); }
__device__ __forceinline__ float Bval(int k, int n) { return (float)((5*k + 11*n) % 9 - 4); }

__global__ void k_probe(int* __restrict__ flag) {
    int lane = threadIdx.x;        // 1 wave
    int lg = lane >> 4, li = lane & 15;
    // hypothesis H0 (two-half): k = 4*lg + j (j<4), 16 + 4*lg + (j-4)
    FR16 fa, fb;
    #pragma unroll
    for (int j = 0; j < 8; j++) {
        int k = (j < 4) ? (4*lg + j) : (16 + 4*lg + (j - 4));
        fa.v[j] = (_Float16)Aval(li, k);
        fb.v[j] = (_Float16)Bval(k, li);
    }
    f32x4 acc = {0.f, 0.f, 0.f, 0.f};
    acc = __builtin_amdgcn_mfma_f32_16x16x32_f16(fa.v, fb.v, acc, 0, 0, 0);
    int ok = 1;
    #pragma unroll
    for (int r = 0; r < 4; r++) {
        int row = 4*lg + r, col = li;
        float ref = 0.f;
        for (int k = 0; k < 32; k++) ref += Aval(row, k) * Bval(k, col);
        if (acc[r] != ref) ok = 0;
    }
    int allok = __all(ok);
    if (lane == 0) *flag = allok ? 0 : 1;   // 0 -> H0, 1 -> H1 (k = 8*lg + j)
}

// ---------------- one iteration, fp16 LDS-staged MFMA with register prefetch ----------------
// grid (TPP/32, NB/32), 256 thr = 4 waves in 2x2; block tile 32(m) x 32(n), K=640.
__global__ __launch_bounds__(256) void k_ifp16(const ushort* __restrict__ SF,
                                               const ushort* __restrict__ ATF,
                                               const float* __restrict__ CT,
                                               const int* __restrict__ map,
                                               const int* __restrict__ flag,
                                               ushort* __restrict__ NF,
                                               float* __restrict__ out, int last) {
    __shared__ ushort SfL[32][IKCH + 8];
    __shared__ ushort AfL[32][IKCH + 8];
    int tid = threadIdx.x;
    int n0 = blockIdx.x * 32;
    int m0 = blockIdx.y * 32;
    int kb = (n0 >= CP) ? 0 : CP;              // k over OPPOSITE panel (global slots)
    int wv = tid >> 6, lane = tid & 63;
    int wm = wv >> 1, wn = wv & 1;
    int lg = lane >> 4, li = lane & 15;
    int hyp = *flag;
    int o0 = hyp ? (8*lg)     : (4*lg);
    int o1 = hyp ? (8*lg + 4) : (16 + 4*lg);
    int srow = tid >> 3, sc = tid & 7;         // staging: 8 threads x 2 us8 per row

    const ushort* sfg = SF + (size_t)(m0 + srow) * TPP + kb;
    const ushort* afg = ATF + (size_t)(n0 + srow) * CP;

    f32x4 c0 = {0.f,0.f,0.f,0.f};

    us8 buf[4];
    #define ISSUE(dst, k0)                                            \
        dst[0] = *(const us8*)(sfg + (k0) + sc * 8);                  \
        dst[1] = *(const us8*)(sfg + (k0) + (sc + 8) * 8);            \
        dst[2] = *(const us8*)(afg + (k0) + sc * 8);                  \
        dst[3] = *(const us8*)(afg + (k0) + (sc + 8) * 8);

    ISSUE(buf, 0)

    #pragma unroll
    for (int ci = 0; ci < CP / IKCH; ci++) {
        __syncthreads();                       // previous chunk's LDS reads done
        *(us8*)&SfL[srow][sc * 8]       = buf[0];
        *(us8*)&SfL[srow][(sc + 8) * 8] = buf[1];
        *(us8*)&AfL[srow][sc * 8]       = buf[2];
        *(us8*)&AfL[srow][(sc + 8) * 8] = buf[3];
        __syncthreads();
        us8 nbuf[4];
        if (ci + 1 < CP / IKCH) { ISSUE(nbuf, (ci + 1) * IKCH) }   // fly under MFMAs
        #pragma unroll
        for (int ks = 0; ks < IKCH / 32; ks++) {
            int ka = ks * 32;
            FR16 fs, fa;
            fs.u[0] = *(const ushort4*)&SfL[wm * 16 + li][ka + o0];
            fs.u[1] = *(const ushort4*)&SfL[wm * 16 + li][ka + o1];
            fa.u[0] = *(const ushort4*)&AfL[wn * 16 + li][ka + o0];
            fa.u[1] = *(const ushort4*)&AfL[wn * 16 + li][ka + o1];
            c0 = __builtin_amdgcn_mfma_f32_16x16x32_f16(fs.v, fa.v, c0, 0, 0, 0);
        }
        if (ci + 1 < CP / IKCH) {
            #pragma unroll
            for (int q = 0; q < 4; q++) buf[q] = nbuf[q];
        }
    }
    #undef ISSUE

    int col = n0 + wn * 16 + li;
    int valid = (map[col] >= 0);
    #pragma unroll
    for (int r = 0; r < 4; r++) {
        int row = m0 + wm * 16 + 4 * lg + r;   // C/D: col=lane&15, row=(lane>>4)*4+reg
        float v = 0.f;
        if (valid) v = sigm(CT[(size_t)row * TPP + col] + c0[r]);
        NF[(size_t)row * TPP + col] = f2u16((_Float16)v);
        if (last && (col == CP - 1 || col == TPP - 1)) {
            int cc = (col == CP - 1) ? 0 : 1;
            out[row * NY + cc] = v;            // full-precision f32 output
        }
    }
}

extern "C" void kernel_launch(void* const* d_in, const int* in_sizes, int n_in,
                              void* d_out, int out_size, void* d_ws, size_t ws_size,
                              hipStream_t stream) {
    const float* Xtr    = (const float*)d_in[0];
    const float* Xdef   = (const float*)d_in[1];
    const float* Xq     = (const float*)d_in[2];
    const float* worder = (const float*)d_in[3];
    const float* wbase  = (const float*)d_in[4];
    const int*   ytr    = (const int*)d_in[5];

    const size_t MATP = (size_t)TPP * TPP * 4;     // 6.55 MB (Es)
    const size_t VECP = (size_t)NB * TPP * 4;      // 1.31 MB (CT)
    const size_t ATB2 = (size_t)TPP * CP * 2;      // 1.64 MB (ATF fp16)
    const size_t SB   = (size_t)NB * TPP * 2;      // 0.655 MB (SF fp16)
    auto need = [&](int ps) {
        return (size_t)(8 * 8192) + MATP + (size_t)ps * 2 * CP * CP * 4
             + ATB2 + VECP + 2 * SB + 65536;
    };
    int psplit = 8;
    if (ws_size < need(8)) psplit = 4;
    if (ws_size < need(4)) psplit = 2;
    if (ws_size < need(2)) psplit = 1;
    int kspan = CP / psplit;                       // 80 / 160 / 320 (multiples of KC)

    char* ws = (char*)d_ws;
    size_t off = 0;
    auto alloc = [&](size_t bytes) {
        void* r = ws + off;
        off += (bytes + 255) & ~(size_t)255;
        return r;
    };
    float*  p    = (float*)alloc((size_t)TP * 4);
    float*  bl   = (float*)alloc((size_t)TP * 4);
    float*  xsq  = (float*)alloc((size_t)TP * 4);
    int*    map  = (int*)  alloc((size_t)TPP * 4);
    float*  pp   = (float*)alloc((size_t)TPP * 4);
    int*    flag = (int*)  alloc(256);
    float*  Es   = (float*)alloc(MATP);
    float*  P    = (float*)alloc((size_t)psplit * 2 * CP * CP * 4);
    ushort* ATF  = (ushort*)alloc(ATB2);
    float*  CT   = (float*)alloc(VECP);
    ushort* SF0  = (ushort*)alloc(SB);
    ushort* SF1  = (ushort*)alloc(SB);

    k_prep<<<TP, 128, 0, stream>>>(Xtr, Xdef, worder, wbase, p, bl, xsq);
    k_perm2<<<1, 1024, 0, stream>>>(ytr, p, map, pp);
    k_es2<<<dim3(TPP / 256, TPP), 256, 0, stream>>>(map, pp, Es);
    k_pblk2<<<dim3(CP / 64, CP / 64, 2 * psplit), 256, 0, stream>>>(Es, P, kspan);
    k_afin2T<<<dim3(CP / 64, TPP / 64), 256, 0, stream>>>(P, psplit, map, pp, Es, ATF);
    k_cq2<<<dim3(TPP / 256, NB), 256, 0, stream>>>(Xtr, Xdef, Xq, bl, map, CT, SF0);
    k_probe<<<1, 64, 0, stream>>>(flag);

    ushort *cf = SF0, *nf = SF1;
    for (int it = 0; it < NITER; it++) {
        k_ifp16<<<dim3(TPP / 32, NB / 32), 256, 0, stream>>>(cf, ATF, CT, map, flag, nf,
                                                             (float*)d_out,
                                                             it == NITER - 1 ? 1 : 0);
        ushort* t = cf; cf = nf; nf = t;
    }
}